// Round 2
// baseline (1533.626 us; speedup 1.0000x reference)
//
#include <hip/hip_runtime.h>
#include <cstdint>

#define CD 64
#define HWD 589824
#define NTILE_N 256
#define K1_BLOCKS (HWD / NTILE_N)   // 2304
#define NSAMP 2048
#define SSTRIDE 288                 // NSAMP * SSTRIDE == HWD
#define CAP 16384
#define PAD_TAU 1.0f
#define FMAXV 3.402823466e+38f

#define AS1 __attribute__((address_space(1)))
#define AS3 __attribute__((address_space(3)))

typedef float f32x16 __attribute__((ext_vector_type(16)));
typedef short bf16x8 __attribute__((ext_vector_type(8)));

__device__ __forceinline__ short f2bf(float f) {
    unsigned u = __float_as_uint(f);
    u = u + 0x7FFFu + ((u >> 16) & 1u);   // RNE
    return (short)(u >> 16);
}

// screen d into unsorted 16-smallest list (rarely taken; K2 only, tiny streams)
#define SCREEN(d, lst, cm)                                                  \
    if ((d) < (cm)) {                                                       \
        bool rep = false;                                                   \
        _Pragma("unroll")                                                   \
        for (int j = 0; j < 16; ++j)                                        \
            if (!rep && lst[j] == (cm)) { lst[j] = (d); rep = true; }       \
        cm = lst[0];                                                        \
        _Pragma("unroll")                                                   \
        for (int j = 1; j < 16; ++j) cm = fmaxf(cm, lst[j]);                \
    }

// K0: per-p threshold tau from a 2048-column sample (exact fp32), + zero counters.
__global__ __launch_bounds__(256) void k0_tau(
    const float* __restrict__ f1, const float* __restrict__ f2,
    const int* __restrict__ nidx, float* __restrict__ tau,
    unsigned* __restrict__ cnt)
{
    const int p = blockIdx.x;
    const int tid = threadIdx.x;
    const int lane = tid & 63, wid = tid >> 6;
    __shared__ float selk[CD];
    __shared__ unsigned long long wmin[4];

    if (tid < CD) selk[tid] = f1[(long)tid * HWD + nidx[p]];
    __syncthreads();
    float sel2 = 0.f;
#pragma unroll
    for (int k = 0; k < CD; ++k) sel2 += selk[k] * selk[k];

    float acc[8], fsq[8];
    long col[8];
#pragma unroll
    for (int c = 0; c < 8; ++c) {
        acc[c] = 0.f; fsq[c] = 0.f;
        col[c] = (long)(c * 256 + tid) * SSTRIDE;
    }
    for (int k = 0; k < CD; ++k) {
        float s = selk[k];
        const float* row = f2 + (long)k * HWD;
#pragma unroll
        for (int c = 0; c < 8; ++c) {
            float v = row[col[c]];
            acc[c] += s * v;
            fsq[c] += v * v;
        }
    }
    float dv[8];
#pragma unroll
    for (int c = 0; c < 8; ++c)
        dv[c] = fmaxf(sel2 + fsq[c] - 2.f * acc[c], 0.f);

    // extract 16 smallest; the 16th defines tau
    float last = 0.f;
    for (int r = 0; r < 16; ++r) {
        float m = dv[0]; int a = 0;
#pragma unroll
        for (int j = 1; j < 8; ++j) if (dv[j] < m) { m = dv[j]; a = j; }
        unsigned long long key =
            ((unsigned long long)__float_as_uint(m) << 32) | (unsigned)(tid * 8 + a);
#pragma unroll
        for (int off = 32; off; off >>= 1) {
            unsigned long long o = __shfl_xor(key, off);
            if (o < key) key = o;
        }
        if (lane == 0) wmin[wid] = key;
        __syncthreads();
        unsigned long long gk = wmin[0];
#pragma unroll
        for (int w = 1; w < 4; ++w) if (wmin[w] < gk) gk = wmin[w];
        last = __uint_as_float((unsigned)(gk >> 32));
        int slot = (int)(gk & 0xFFFFFFFFu);
        if ((slot >> 3) == tid) {
#pragma unroll
            for (int j = 0; j < 8; ++j) if (j == (slot & 7)) dv[j] = FMAXV;
        }
        __syncthreads();
    }
    if (tid == 0) { tau[p] = last + PAD_TAU; cnt[p] = 0u; }
}

// K1: one 256-column tile per block. global_load_lds staging -> MFMA -> filter.
__global__ __launch_bounds__(256, 2) void k1_dist(
    const float* __restrict__ f1, const float* __restrict__ f2,
    const int* __restrict__ nidx, const float* __restrict__ tau,
    float* __restrict__ surv, unsigned* __restrict__ cnt)
{
    __shared__ float lds[CD][NTILE_N];   // 64 KB
    const int tid = threadIdx.x;
    const int lane = tid & 63;
    const int wid = tid >> 6;
    const int l31 = lane & 31;
    const int lh = lane >> 5;
    const long n0 = (long)blockIdx.x * NTILE_N;

    // stage f2 tile: wave wid loads k rows [wid*16, wid*16+16), 1 KB per instr
#pragma unroll
    for (int kk = 0; kk < 16; ++kk) {
        int k = wid * 16 + kk;
        const float* gp = f2 + (long)k * HWD + n0 + lane * 4;
        __builtin_amdgcn_global_load_lds((const AS1 void*)gp,
                                         (AS3 void*)&lds[k][0], 16, 0, 0);
    }

    // sel B-fragments (gather, L2-hot) — overlaps staging latency
    bf16x8 selfrag[2][4];
    float sel2[2];
#pragma unroll
    for (int b = 0; b < 2; ++b) {
        long colb = (long)nidx[l31 + 32 * b];
        float s2 = 0.f;
#pragma unroll
        for (int ks = 0; ks < 4; ++ks) {
            bf16x8 fr;
#pragma unroll
            for (int j = 0; j < 8; ++j) {
                float v = f1[(long)(16 * ks + 8 * lh + j) * HWD + colb];
                s2 += v * v;
                fr[j] = f2bf(v);
            }
            selfrag[b][ks] = fr;
        }
        s2 += __shfl_xor(s2, 32);
        sel2[b] = s2;
    }
    const float taup0 = tau[l31];
    const float taup1 = tau[l31 + 32];

    __syncthreads();   // drains vmcnt -> LDS tile ready

    f32x16 acc[2][2];  // [n-group][p-block]
    float fsv[2];
#pragma unroll
    for (int g = 0; g < 2; ++g) {
        float fs = 0.f;
        bf16x8 af[4];
#pragma unroll
        for (int ks = 0; ks < 4; ++ks) {
            bf16x8 fr;
#pragma unroll
            for (int j = 0; j < 8; ++j) {
                float v = lds[16 * ks + 8 * lh + j][wid * 64 + g * 32 + l31];
                fs += v * v;
                fr[j] = f2bf(v);
            }
            af[ks] = fr;
        }
        fs += __shfl_xor(fs, 32);   // combine k-halves (same column)
        fsv[g] = fs;
#pragma unroll
        for (int i = 0; i < 16; ++i) { acc[g][0][i] = 0.f; acc[g][1][i] = 0.f; }
#pragma unroll
        for (int ks = 0; ks < 4; ++ks) {
            acc[g][0] = __builtin_amdgcn_mfma_f32_32x32x16_bf16(af[ks], selfrag[0][ks], acc[g][0], 0, 0, 0);
            acc[g][1] = __builtin_amdgcn_mfma_f32_32x32x16_bf16(af[ks], selfrag[1][ks], acc[g][1], 0, 0, 0);
        }
    }

    // filter: d <= tau_p -> append (rare: ~0.8% of values)
#pragma unroll
    for (int g = 0; g < 2; ++g) {
#pragma unroll
        for (int i = 0; i < 16; ++i) {
            int r = (i & 3) + 8 * (i >> 2) + 4 * lh;
            float fr2 = __shfl(fsv[g], r);
            float d0 = fmaxf(sel2[0] + fr2 - 2.f * acc[g][0][i], 0.f);
            if (d0 <= taup0) {
                unsigned idx = atomicAdd(&cnt[l31], 1u);
                if (idx < CAP) surv[(long)l31 * CAP + idx] = d0;
            }
            float d1 = fmaxf(sel2[1] + fr2 - 2.f * acc[g][1][i], 0.f);
            if (d1 <= taup1) {
                unsigned idx = atomicAdd(&cnt[l31 + 32], 1u);
                if (idx < CAP) surv[(long)(l31 + 32) * CAP + idx] = d1;
            }
        }
    }
}

// K2: exact 16 smallest among survivors of p; sum them.
__global__ __launch_bounds__(256) void k2_select(
    const float* __restrict__ surv, const unsigned* __restrict__ cnt,
    float* __restrict__ partial)
{
    const int p = blockIdx.x;
    const int tid = threadIdx.x;
    const int lane = tid & 63, wid = tid >> 6;
    __shared__ unsigned long long wmin[4];
    unsigned m = cnt[p]; if (m > CAP) m = CAP;
    const float* base = surv + (long)p * CAP;

    float lst[16];
#pragma unroll
    for (int j = 0; j < 16; ++j) lst[j] = FMAXV;
    float cm = FMAXV;
    for (unsigned i = tid; i < m; i += 256) {
        float d = base[i];
        SCREEN(d, lst, cm);
    }

    float sum = 0.f;
    for (int r = 0; r < 16; ++r) {
        float mn = lst[0]; int a = 0;
#pragma unroll
        for (int j = 1; j < 16; ++j) if (lst[j] < mn) { mn = lst[j]; a = j; }
        unsigned long long key =
            ((unsigned long long)__float_as_uint(mn) << 32) | (unsigned)(tid * 16 + a);
#pragma unroll
        for (int off = 32; off; off >>= 1) {
            unsigned long long o = __shfl_xor(key, off);
            if (o < key) key = o;
        }
        if (lane == 0) wmin[wid] = key;
        __syncthreads();
        unsigned long long gk = wmin[0];
#pragma unroll
        for (int w = 1; w < 4; ++w) if (wmin[w] < gk) gk = wmin[w];
        sum += __uint_as_float((unsigned)(gk >> 32));
        int slot = (int)(gk & 0xFFFFFFFFu);
        if ((slot >> 4) == tid) {
#pragma unroll
            for (int j = 0; j < 16; ++j) if (j == (slot & 15)) lst[j] = FMAXV;
        }
        __syncthreads();
    }
    if (tid == 0) partial[p] = sum;
}

__global__ void k3_final(const float* __restrict__ partial, float* __restrict__ out)
{
    float v = partial[threadIdx.x];   // 64 threads
#pragma unroll
    for (int off = 32; off; off >>= 1) v += __shfl_xor(v, off);
    if (threadIdx.x == 0) out[0] = -v / 1024.0f;
}

extern "C" void kernel_launch(void* const* d_in, const int* in_sizes, int n_in,
                              void* d_out, int out_size, void* d_ws, size_t ws_size,
                              hipStream_t stream)
{
    const float* f1   = (const float*)d_in[0];
    const float* f2   = (const float*)d_in[1];
    const int*   nidx = (const int*)d_in[3];     // negative_indices
    float* out = (float*)d_out;

    float*    surv    = (float*)d_ws;                       // 64*16384 = 4 MB
    float*    tau     = surv + (long)CD * CAP;
    unsigned* cnt     = (unsigned*)(tau + CD);
    float*    partial = (float*)(cnt + CD);

    k0_tau  <<<CD,        256, 0, stream>>>(f1, f2, nidx, tau, cnt);
    k1_dist <<<K1_BLOCKS, 256, 0, stream>>>(f1, f2, nidx, tau, surv, cnt);
    k2_select<<<CD,       256, 0, stream>>>(surv, cnt, partial);
    k3_final<<<1, 64, 0, stream>>>(partial, out);
}

// Round 3
// 610.526 us; speedup vs baseline: 2.5120x; 2.5120x over previous
//
#include <hip/hip_runtime.h>
#include <cstdint>

#define CD 64
#define HWD 589824
#define NSAMP 8192
#define PAD_TAU 0.75f
#define NTILE 32
#define TILES (HWD / NTILE)         // 18432
#define K1_BLOCKS 1536
#define K1_WAVES (K1_BLOCKS * 4)    // 6144
#define TPW (TILES / K1_WAVES)      // 3
#define CAPC 4
#define NCELL ((long)CD * K1_WAVES * 2)   // 786432 cells
#define FMAXV 3.402823466e+38f

typedef float f32x16 __attribute__((ext_vector_type(16)));
typedef short bf16x8 __attribute__((ext_vector_type(8)));

__device__ __forceinline__ short f2bf(float f) {
    unsigned u = __float_as_uint(f);
    u = u + 0x7FFFu + ((u >> 16) & 1u);   // RNE
    return (short)(u >> 16);
}

// exact 16-smallest screen (static indexing only)
#define SCREEN(d, lst, cm)                                                  \
    if ((d) < (cm)) {                                                       \
        bool rep = false;                                                   \
        _Pragma("unroll")                                                   \
        for (int j = 0; j < 16; ++j)                                        \
            if (!rep && lst[j] == (cm)) { lst[j] = (d); rep = true; }       \
        cm = lst[0];                                                        \
        _Pragma("unroll")                                                   \
        for (int j = 1; j < 16; ++j) cm = fmaxf(cm, lst[j]);                \
    }

// K0: blocks 0..63 -> tau[p] from 8192 contiguous sample columns (exact fp32).
//     block 64     -> pack sel bf16 B-fragments + ||sel||^2 (one wave).
__global__ __launch_bounds__(256) void k0_prep(
    const float* __restrict__ f1, const float* __restrict__ f2,
    const int* __restrict__ nidx, float* __restrict__ tau,
    bf16x8* __restrict__ selpack, float* __restrict__ sel2p)
{
    if (blockIdx.x == CD) {            // ---- pack path (one wave) ----
        const int lane = threadIdx.x;
        if (lane >= 64) return;
        const int l31 = lane & 31, lh = lane >> 5;
#pragma unroll
        for (int b = 0; b < 2; ++b) {
            long colb = (long)nidx[l31 + 32 * b];
            float s2 = 0.f;
#pragma unroll
            for (int ks = 0; ks < 4; ++ks) {
                bf16x8 fr;
#pragma unroll
                for (int j = 0; j < 8; ++j) {
                    float v = f1[(long)(16 * ks + 8 * lh + j) * HWD + colb];
                    s2 += v * v;
                    fr[j] = f2bf(v);
                }
                selpack[(b * 4 + ks) * 64 + lane] = fr;
            }
            s2 += __shfl_xor(s2, 32);
            sel2p[b * 64 + lane] = s2;
        }
        return;
    }
    // ---- tau path ----
    const int p = blockIdx.x;
    const int tid = threadIdx.x;
    const int lane = tid & 63, wid = tid >> 6;
    __shared__ float selk[CD];
    __shared__ unsigned long long wmin[4];

    if (tid < CD) selk[tid] = f1[(long)tid * HWD + nidx[p]];
    __syncthreads();
    float sel2 = 0.f;
#pragma unroll
    for (int k = 0; k < CD; ++k) sel2 += selk[k] * selk[k];

    float acc[32], fsq[32];
#pragma unroll
    for (int c = 0; c < 32; ++c) { acc[c] = 0.f; fsq[c] = 0.f; }
    for (int k = 0; k < CD; ++k) {
        float s = selk[k];
        const float* row = f2 + (long)k * HWD + tid;   // coalesced
#pragma unroll
        for (int c = 0; c < 32; ++c) {
            float v = row[c * 256];
            acc[c] += s * v;
            fsq[c] += v * v;
        }
    }

    float lst[16];
#pragma unroll
    for (int j = 0; j < 16; ++j) lst[j] = FMAXV;
    float cm = FMAXV;
#pragma unroll
    for (int c = 0; c < 32; ++c) {
        float d = fmaxf(sel2 + fsq[c] - 2.f * acc[c], 0.f);
        SCREEN(d, lst, cm);
    }

    float last = 0.f;
    for (int r = 0; r < 16; ++r) {
        float mn = lst[0]; int a = 0;
#pragma unroll
        for (int j = 1; j < 16; ++j) if (lst[j] < mn) { mn = lst[j]; a = j; }
        unsigned long long key =
            ((unsigned long long)__float_as_uint(mn) << 32) | (unsigned)(tid * 16 + a);
#pragma unroll
        for (int off = 32; off; off >>= 1) {
            unsigned long long o = __shfl_xor(key, off);
            if (o < key) key = o;
        }
        if (lane == 0) wmin[wid] = key;
        __syncthreads();
        unsigned long long gk = wmin[0];
#pragma unroll
        for (int w = 1; w < 4; ++w) if (wmin[w] < gk) gk = wmin[w];
        last = __uint_as_float((unsigned)(gk >> 32));
        int slot = (int)(gk & 0xFFFFFFFFu);
        if ((slot >> 4) == tid) {
#pragma unroll
            for (int j = 0; j < 16; ++j) if (j == (slot & 15)) lst[j] = FMAXV;
        }
        __syncthreads();
    }
    if (tid == 0) tau[p] = last + PAD_TAU;
}

// K1: stream f2 in VGPRs, MFMA distances, filter vs tau into per-cell
// private regions (NO atomics, no LDS).
__global__ __launch_bounds__(256, 2) void k1_dist(
    const float* __restrict__ f2, const bf16x8* __restrict__ selpack,
    const float* __restrict__ sel2p, const float* __restrict__ tau,
    float* __restrict__ surv, unsigned* __restrict__ cnt)
{
    const int tid = threadIdx.x;
    const int lane = tid & 63, wid = tid >> 6;
    const int l31 = lane & 31, lh = lane >> 5;
    const int gw = blockIdx.x * 4 + wid;        // 0..6143

    bf16x8 selfrag[2][4];
#pragma unroll
    for (int b = 0; b < 2; ++b)
#pragma unroll
        for (int ks = 0; ks < 4; ++ks)
            selfrag[b][ks] = selpack[(b * 4 + ks) * 64 + lane];
    const float sel20 = sel2p[lane], sel21 = sel2p[64 + lane];
    const float tau0 = tau[l31], tau1 = tau[l31 + 32];

    // private cells: cell(p, gw, lh)
    const long cell0 = ((long)l31 * K1_WAVES + gw) * 2 + lh;
    const long cell1 = ((long)(l31 + 32) * K1_WAVES + gw) * 2 + lh;
    float* sb0 = surv + cell0 * CAPC;
    float* sb1 = surv + cell1 * CAPC;
    unsigned c0 = 0, c1 = 0;

    for (int t = 0; t < TPW; ++t) {
        const long n0 = (long)(gw * TPW + t) * NTILE;
        const float* fp = f2 + n0 + l31;

        float av[4][8];
#pragma unroll
        for (int ks = 0; ks < 4; ++ks)
#pragma unroll
            for (int j = 0; j < 8; ++j)
                av[ks][j] = fp[(long)(16 * ks + 8 * lh + j) * HWD];

        float fs = 0.f;
        bf16x8 af[4];
#pragma unroll
        for (int ks = 0; ks < 4; ++ks) {
#pragma unroll
            for (int j = 0; j < 8; ++j) {
                float v = av[ks][j];
                fs += v * v;
                af[ks][j] = f2bf(v);
            }
        }
        fs += __shfl_xor(fs, 32);   // combine k-halves (same column n)

        f32x16 acc0, acc1;
#pragma unroll
        for (int i = 0; i < 16; ++i) { acc0[i] = 0.f; acc1[i] = 0.f; }
#pragma unroll
        for (int ks = 0; ks < 4; ++ks) {
            acc0 = __builtin_amdgcn_mfma_f32_32x32x16_bf16(af[ks], selfrag[0][ks], acc0, 0, 0, 0);
            acc1 = __builtin_amdgcn_mfma_f32_32x32x16_bf16(af[ks], selfrag[1][ks], acc1, 0, 0, 0);
        }

#pragma unroll
        for (int i = 0; i < 16; ++i) {
            int r = (i & 3) + 8 * (i >> 2) + 4 * lh;
            float fr2 = __shfl(fs, r);
            float d0 = fmaxf(sel20 + fr2 - 2.f * acc0[i], 0.f);
            if (d0 <= tau0) { if (c0 < CAPC) sb0[c0] = d0; ++c0; }
            float d1 = fmaxf(sel21 + fr2 - 2.f * acc1[i], 0.f);
            if (d1 <= tau1) { if (c1 < CAPC) sb1[c1] = d1; ++c1; }
        }
    }
    cnt[cell0] = (c0 < CAPC) ? c0 : CAPC;
    cnt[cell1] = (c1 < CAPC) ? c1 : CAPC;
}

// K2: block p merges its ~12K cells -> exact 16 smallest -> sum.
__global__ __launch_bounds__(256) void k2_select(
    const float* __restrict__ surv, const unsigned* __restrict__ cnt,
    float* __restrict__ partial)
{
    const int p = blockIdx.x;
    const int tid = threadIdx.x;
    const int lane = tid & 63, wid = tid >> 6;
    __shared__ unsigned long long wmin[4];
    const unsigned* cb = cnt + (long)p * K1_WAVES * 2;
    const float* sb = surv + (long)p * K1_WAVES * 2 * CAPC;

    float lst[16];
#pragma unroll
    for (int j = 0; j < 16; ++j) lst[j] = FMAXV;
    float cm = FMAXV;

    for (int cell = tid; cell < K1_WAVES * 2; cell += 256) {
        unsigned c = cb[cell];
        if (c > CAPC) c = CAPC;
        const float* sp = sb + (long)cell * CAPC;
        for (unsigned j = 0; j < c; ++j) {
            float d = sp[j];
            SCREEN(d, lst, cm);
        }
    }

    float sum = 0.f;
    for (int r = 0; r < 16; ++r) {
        float mn = lst[0]; int a = 0;
#pragma unroll
        for (int j = 1; j < 16; ++j) if (lst[j] < mn) { mn = lst[j]; a = j; }
        unsigned long long key =
            ((unsigned long long)__float_as_uint(mn) << 32) | (unsigned)(tid * 16 + a);
#pragma unroll
        for (int off = 32; off; off >>= 1) {
            unsigned long long o = __shfl_xor(key, off);
            if (o < key) key = o;
        }
        if (lane == 0) wmin[wid] = key;
        __syncthreads();
        unsigned long long gk = wmin[0];
#pragma unroll
        for (int w = 1; w < 4; ++w) if (wmin[w] < gk) gk = wmin[w];
        sum += __uint_as_float((unsigned)(gk >> 32));
        int slot = (int)(gk & 0xFFFFFFFFu);
        if ((slot >> 4) == tid) {
#pragma unroll
            for (int j = 0; j < 16; ++j) if (j == (slot & 15)) lst[j] = FMAXV;
        }
        __syncthreads();
    }
    if (tid == 0) partial[p] = sum;
}

__global__ void k3_final(const float* __restrict__ partial, float* __restrict__ out)
{
    float v = partial[threadIdx.x];   // 64 threads
#pragma unroll
    for (int off = 32; off; off >>= 1) v += __shfl_xor(v, off);
    if (threadIdx.x == 0) out[0] = -v / 1024.0f;
}

extern "C" void kernel_launch(void* const* d_in, const int* in_sizes, int n_in,
                              void* d_out, int out_size, void* d_ws, size_t ws_size,
                              hipStream_t stream)
{
    const float* f1   = (const float*)d_in[0];
    const float* f2   = (const float*)d_in[1];
    const int*   nidx = (const int*)d_in[3];     // negative_indices
    float* out = (float*)d_out;

    float*    surv    = (float*)d_ws;                         // 786432*4 floats = 12.6 MB
    unsigned* cnt     = (unsigned*)(surv + NCELL * CAPC);     // 3.1 MB
    bf16x8*   selpack = (bf16x8*)(cnt + NCELL);               // 8 KB (16B aligned)
    float*    sel2p   = (float*)(selpack + 8 * 64);           // 512 B
    float*    tau     = sel2p + 128;
    float*    partial = tau + CD;

    k0_prep <<<CD + 1,    256, 0, stream>>>(f1, f2, nidx, tau, selpack, sel2p);
    k1_dist <<<K1_BLOCKS, 256, 0, stream>>>(f2, selpack, sel2p, tau, surv, cnt);
    k2_select<<<CD,       256, 0, stream>>>(surv, cnt, partial);
    k3_final <<<1, 64, 0, stream>>>(partial, out);
}

// Round 4
// 158.811 us; speedup vs baseline: 9.6569x; 3.8444x over previous
//
#include <hip/hip_runtime.h>
#include <cstdint>

#define CD 64
#define HWD 589824
#define NSAMP 8192
#define STILES (NSAMP / 32)         // 256
#define PAD_TAU 0.25f
#define NTILE 32
#define TILES (HWD / NTILE)         // 18432
#define K1_BLOCKS 1536
#define K1_WAVES (K1_BLOCKS * 4)    // 6144
#define TPW (TILES / K1_WAVES)      // 3
#define CAPC 4
#define NCELL ((long)CD * K1_WAVES * 2)   // 786432 cells
#define FMAXV 3.402823466e+38f

typedef float f32x16 __attribute__((ext_vector_type(16)));
typedef short bf16x8 __attribute__((ext_vector_type(8)));

__device__ __forceinline__ short f2bf(float f) {
    unsigned u = __float_as_uint(f);
    u = u + 0x7FFFu + ((u >> 16) & 1u);   // RNE
    return (short)(u >> 16);
}

// exact 16-smallest screen (static indexing only)
#define SCREEN(d, lst, cm)                                                  \
    if ((d) < (cm)) {                                                       \
        bool rep = false;                                                   \
        _Pragma("unroll")                                                   \
        for (int j = 0; j < 16; ++j)                                        \
            if (!rep && lst[j] == (cm)) { lst[j] = (d); rep = true; }       \
        cm = lst[0];                                                        \
        _Pragma("unroll")                                                   \
        for (int j = 1; j < 16; ++j) cm = fmaxf(cm, lst[j]);                \
    }

// Shared tile engine: d(p, n0+.) for 32 columns x 64 p. Convert-as-you-load
// (av[8] reused across k-slices -> small live set, 8-load batches).
__device__ __forceinline__ void tile_dist(
    const float* __restrict__ fp,          // f2 + n0 + l31
    const bf16x8* __restrict__ sf0, const bf16x8* __restrict__ sf1,
    int lh, f32x16& acc0, f32x16& acc1, float& fs)
{
    fs = 0.f;
#pragma unroll
    for (int i = 0; i < 16; ++i) { acc0[i] = 0.f; acc1[i] = 0.f; }
#pragma unroll
    for (int ks = 0; ks < 4; ++ks) {
        float av[8];
#pragma unroll
        for (int j = 0; j < 8; ++j)
            av[j] = fp[(long)(16 * ks + 8 * lh + j) * HWD];
        bf16x8 af;
#pragma unroll
        for (int j = 0; j < 8; ++j) {
            fs += av[j] * av[j];
            af[j] = f2bf(av[j]);
        }
        acc0 = __builtin_amdgcn_mfma_f32_32x32x16_bf16(af, sf0[ks], acc0, 0, 0, 0);
        acc1 = __builtin_amdgcn_mfma_f32_32x32x16_bf16(af, sf1[ks], acc1, 0, 0, 0);
    }
    fs += __shfl_xor(fs, 32);   // combine k-halves (same column n)
}

// k_pack: one wave packs sel bf16 B-fragments + ||sel||^2.
__global__ void k_pack(const float* __restrict__ f1, const int* __restrict__ nidx,
                       bf16x8* __restrict__ selpack, float* __restrict__ sel2p)
{
    const int lane = threadIdx.x;          // 64 threads
    const int l31 = lane & 31, lh = lane >> 5;
#pragma unroll
    for (int b = 0; b < 2; ++b) {
        long colb = (long)nidx[l31 + 32 * b];
        float s2 = 0.f;
#pragma unroll
        for (int ks = 0; ks < 4; ++ks) {
            bf16x8 fr;
#pragma unroll
            for (int j = 0; j < 8; ++j) {
                float v = f1[(long)(16 * ks + 8 * lh + j) * HWD + colb];
                s2 += v * v;
                fr[j] = f2bf(v);
            }
            selpack[(b * 4 + ks) * 64 + lane] = fr;
        }
        s2 += __shfl_xor(s2, 32);
        sel2p[b * 64 + lane] = s2;
    }
}

// k0a: 256 one-wave blocks; tile t = blockIdx over sample columns 0..8191.
// Writes dsT[n][p] (coalesced across p).
__global__ __launch_bounds__(64) void k0a_sample(
    const float* __restrict__ f2, const bf16x8* __restrict__ selpack,
    const float* __restrict__ sel2p, float* __restrict__ dsT)
{
    const int lane = threadIdx.x;
    const int l31 = lane & 31, lh = lane >> 5;
    const long n0 = (long)blockIdx.x * NTILE;

    bf16x8 sf0[4], sf1[4];
#pragma unroll
    for (int ks = 0; ks < 4; ++ks) {
        sf0[ks] = selpack[ks * 64 + lane];
        sf1[ks] = selpack[(4 + ks) * 64 + lane];
    }
    const float sel20 = sel2p[lane], sel21 = sel2p[64 + lane];

    f32x16 acc0, acc1; float fs;
    tile_dist(f2 + n0 + l31, sf0, sf1, lh, acc0, acc1, fs);

#pragma unroll
    for (int i = 0; i < 16; ++i) {
        int r = (i & 3) + 8 * (i >> 2) + 4 * lh;
        float fr2 = __shfl(fs, r);
        dsT[(n0 + r) * 64 + l31]      = fmaxf(sel20 + fr2 - 2.f * acc0[i], 0.f);
        dsT[(n0 + r) * 64 + 32 + l31] = fmaxf(sel21 + fr2 - 2.f * acc1[i], 0.f);
    }
}

// k0b: block p -> 16th smallest of dsT[:, p] + pad = tau[p].
__global__ __launch_bounds__(256) void k0b_tau(
    const float* __restrict__ dsT, float* __restrict__ tau)
{
    const int p = blockIdx.x;
    const int tid = threadIdx.x;
    const int lane = tid & 63, wid = tid >> 6;
    __shared__ unsigned long long wmin[4];

    float lst[16];
#pragma unroll
    for (int j = 0; j < 16; ++j) lst[j] = FMAXV;
    float cm = FMAXV;
#pragma unroll
    for (int c = 0; c < NSAMP / 256; ++c) {
        float d = dsT[(long)(c * 256 + tid) * 64 + p];
        SCREEN(d, lst, cm);
    }

    float last = 0.f;
    for (int r = 0; r < 16; ++r) {
        float mn = lst[0]; int a = 0;
#pragma unroll
        for (int j = 1; j < 16; ++j) if (lst[j] < mn) { mn = lst[j]; a = j; }
        unsigned long long key =
            ((unsigned long long)__float_as_uint(mn) << 32) | (unsigned)(tid * 16 + a);
#pragma unroll
        for (int off = 32; off; off >>= 1) {
            unsigned long long o = __shfl_xor(key, off);
            if (o < key) key = o;
        }
        if (lane == 0) wmin[wid] = key;
        __syncthreads();
        unsigned long long gk = wmin[0];
#pragma unroll
        for (int w = 1; w < 4; ++w) if (wmin[w] < gk) gk = wmin[w];
        last = __uint_as_float((unsigned)(gk >> 32));
        int slot = (int)(gk & 0xFFFFFFFFu);
        if ((slot >> 4) == tid) {
#pragma unroll
            for (int j = 0; j < 16; ++j) if (j == (slot & 15)) lst[j] = FMAXV;
        }
        __syncthreads();
    }
    if (tid == 0) tau[p] = last + PAD_TAU;
}

// K1: stream f2, MFMA distances, filter vs tau into private cells (no atomics).
__global__ __launch_bounds__(256) void k1_dist(
    const float* __restrict__ f2, const bf16x8* __restrict__ selpack,
    const float* __restrict__ sel2p, const float* __restrict__ tau,
    float* __restrict__ surv, unsigned* __restrict__ cnt)
{
    const int tid = threadIdx.x;
    const int lane = tid & 63, wid = tid >> 6;
    const int l31 = lane & 31, lh = lane >> 5;
    const int gw = blockIdx.x * 4 + wid;        // 0..6143

    bf16x8 sf0[4], sf1[4];
#pragma unroll
    for (int ks = 0; ks < 4; ++ks) {
        sf0[ks] = selpack[ks * 64 + lane];
        sf1[ks] = selpack[(4 + ks) * 64 + lane];
    }
    const float sel20 = sel2p[lane], sel21 = sel2p[64 + lane];
    const float tau0 = tau[l31], tau1 = tau[l31 + 32];

    const long cell0 = ((long)l31 * K1_WAVES + gw) * 2 + lh;
    const long cell1 = ((long)(l31 + 32) * K1_WAVES + gw) * 2 + lh;
    float* sb0 = surv + cell0 * CAPC;
    float* sb1 = surv + cell1 * CAPC;
    unsigned c0 = 0, c1 = 0;

    for (int t = 0; t < TPW; ++t) {
        const long n0 = (long)(gw * TPW + t) * NTILE;
        f32x16 acc0, acc1; float fs;
        tile_dist(f2 + n0 + l31, sf0, sf1, lh, acc0, acc1, fs);

#pragma unroll
        for (int i = 0; i < 16; ++i) {
            int r = (i & 3) + 8 * (i >> 2) + 4 * lh;
            float fr2 = __shfl(fs, r);
            float d0 = fmaxf(sel20 + fr2 - 2.f * acc0[i], 0.f);
            if (d0 <= tau0) { if (c0 < CAPC) sb0[c0] = d0; ++c0; }
            float d1 = fmaxf(sel21 + fr2 - 2.f * acc1[i], 0.f);
            if (d1 <= tau1) { if (c1 < CAPC) sb1[c1] = d1; ++c1; }
        }
    }
    cnt[cell0] = (c0 < CAPC) ? c0 : CAPC;
    cnt[cell1] = (c1 < CAPC) ? c1 : CAPC;
}

// K2: block p merges its cells -> exact 16 smallest -> sum.
__global__ __launch_bounds__(256) void k2_select(
    const float* __restrict__ surv, const unsigned* __restrict__ cnt,
    float* __restrict__ partial)
{
    const int p = blockIdx.x;
    const int tid = threadIdx.x;
    const int lane = tid & 63, wid = tid >> 6;
    __shared__ unsigned long long wmin[4];
    const unsigned* cb = cnt + (long)p * K1_WAVES * 2;
    const float* sb = surv + (long)p * K1_WAVES * 2 * CAPC;

    float lst[16];
#pragma unroll
    for (int j = 0; j < 16; ++j) lst[j] = FMAXV;
    float cm = FMAXV;

    for (int cell = tid; cell < K1_WAVES * 2; cell += 256) {
        unsigned c = cb[cell];
        if (c > CAPC) c = CAPC;
        const float* sp = sb + (long)cell * CAPC;
        for (unsigned j = 0; j < c; ++j) {
            float d = sp[j];
            SCREEN(d, lst, cm);
        }
    }

    float sum = 0.f;
    for (int r = 0; r < 16; ++r) {
        float mn = lst[0]; int a = 0;
#pragma unroll
        for (int j = 1; j < 16; ++j) if (lst[j] < mn) { mn = lst[j]; a = j; }
        unsigned long long key =
            ((unsigned long long)__float_as_uint(mn) << 32) | (unsigned)(tid * 16 + a);
#pragma unroll
        for (int off = 32; off; off >>= 1) {
            unsigned long long o = __shfl_xor(key, off);
            if (o < key) key = o;
        }
        if (lane == 0) wmin[wid] = key;
        __syncthreads();
        unsigned long long gk = wmin[0];
#pragma unroll
        for (int w = 1; w < 4; ++w) if (wmin[w] < gk) gk = wmin[w];
        sum += __uint_as_float((unsigned)(gk >> 32));
        int slot = (int)(gk & 0xFFFFFFFFu);
        if ((slot >> 4) == tid) {
#pragma unroll
            for (int j = 0; j < 16; ++j) if (j == (slot & 15)) lst[j] = FMAXV;
        }
        __syncthreads();
    }
    if (tid == 0) partial[p] = sum;
}

__global__ void k3_final(const float* __restrict__ partial, float* __restrict__ out)
{
    float v = partial[threadIdx.x];   // 64 threads
#pragma unroll
    for (int off = 32; off; off >>= 1) v += __shfl_xor(v, off);
    if (threadIdx.x == 0) out[0] = -v / 1024.0f;
}

extern "C" void kernel_launch(void* const* d_in, const int* in_sizes, int n_in,
                              void* d_out, int out_size, void* d_ws, size_t ws_size,
                              hipStream_t stream)
{
    const float* f1   = (const float*)d_in[0];
    const float* f2   = (const float*)d_in[1];
    const int*   nidx = (const int*)d_in[3];     // negative_indices
    float* out = (float*)d_out;

    float*    surv    = (float*)d_ws;                      // 12.6 MB
    float*    dsT     = (float*)d_ws;                      // 2 MB, aliases surv
                                                           // (consumed before k1 writes)
    unsigned* cnt     = (unsigned*)(surv + NCELL * CAPC);  // 3.1 MB
    bf16x8*   selpack = (bf16x8*)(cnt + NCELL);            // 8 KB, 16B-aligned
    float*    sel2p   = (float*)(selpack + 8 * 64);
    float*    tau     = sel2p + 128;
    float*    partial = tau + CD;

    k_pack   <<<1,         64, 0, stream>>>(f1, nidx, selpack, sel2p);
    k0a_sample<<<STILES,   64, 0, stream>>>(f2, selpack, sel2p, dsT);
    k0b_tau  <<<CD,       256, 0, stream>>>(dsT, tau);
    k1_dist  <<<K1_BLOCKS,256, 0, stream>>>(f2, selpack, sel2p, tau, surv, cnt);
    k2_select<<<CD,       256, 0, stream>>>(surv, cnt, partial);
    k3_final <<<1,         64, 0, stream>>>(partial, out);
}